// Round 7
// baseline (516.497 us; speedup 1.0000x reference)
//
#include <hip/hip_runtime.h>

typedef __attribute__((ext_vector_type(8))) short s8v;
typedef __attribute__((ext_vector_type(4))) float f4v;

__device__ __forceinline__ unsigned short f2bf(float f) {
  unsigned int u = __float_as_uint(f);
  u += 0x7FFFu + ((u >> 16) & 1u);   // RNE
  return (unsigned short)(u >> 16);
}
__device__ __forceinline__ float bf2f(unsigned short s) {
  return __uint_as_float(((unsigned int)s) << 16);
}

// async global->LDS 16B: lane i deposits at wave-uniform base + i*16
__device__ __forceinline__ void gld16(const void* g, void* l) {
  __builtin_amdgcn_global_load_lds(
      (const __attribute__((address_space(1))) unsigned int*)g,
      (__attribute__((address_space(3))) unsigned int*)l, 16, 0, 0);
}

// counted waits + raw barrier, all memory-clobbered so no LDS/VMEM op is
// scheduled across them (correctness of the pipelined K-loop depends on it).
#define WAITVM4() asm volatile("s_waitcnt vmcnt(4)" ::: "memory")
#define WAITVM2() asm volatile("s_waitcnt vmcnt(2)" ::: "memory")
#define WAITVM0() asm volatile("s_waitcnt vmcnt(0)" ::: "memory")
#define WAITLGKM() asm volatile("s_waitcnt lgkmcnt(0)" ::: "memory")
#define SBAR() asm volatile("s_barrier" ::: "memory")

// ---------------------------------------------------------------------------
// Pass 0a: X fp32 [65536,512] -> Xbf bf16.
// ---------------------------------------------------------------------------
__global__ __launch_bounds__(256)
void convert_x_kernel(const float* __restrict__ X, unsigned short* __restrict__ Xbf)
{
  size_t base = ((size_t)blockIdx.x * 256 + threadIdx.x) * 8;
  float4 a = *(const float4*)&X[base];
  float4 b = *(const float4*)&X[base + 4];
  s8v p = (s8v){ (short)f2bf(a.x), (short)f2bf(a.y), (short)f2bf(a.z), (short)f2bf(a.w),
                 (short)f2bf(b.x), (short)f2bf(b.y), (short)f2bf(b.z), (short)f2bf(b.w) };
  *(s8v*)&Xbf[base] = p;
}

// ---------------------------------------------------------------------------
// Pass 0b: Wt[n][k] bf16, n = 0..511 Wq | 512..1023 Wk | 1024..1535 Wv.
// ---------------------------------------------------------------------------
__global__ __launch_bounds__(256)
void transpose_w_kernel(const float* __restrict__ Wq, const float* __restrict__ Wk,
                        const float* __restrict__ Wv, unsigned short* __restrict__ Wt)
{
  __shared__ float T[64][68];
  const int kt = blockIdx.x, nt = blockIdx.y;
  const float* W = (nt < 8) ? Wq : (nt < 16 ? Wk : Wv);
  const int n0 = (nt & 7) * 64, k0 = kt * 64;
  const int t = threadIdx.x;
  #pragma unroll
  for (int it = 0; it < 4; ++it) {
    int idx = it * 256 + t;
    int k = idx >> 4, n4 = (idx & 15) << 2;
    *(float4*)&T[k][n4] = *(const float4*)&W[(size_t)(k0 + k) * 512 + n0 + n4];
  }
  __syncthreads();
  #pragma unroll
  for (int it = 0; it < 2; ++it) {
    int idx = it * 256 + t;
    int n = idx >> 3, k8 = (idx & 7) << 3;
    s8v p;
    #pragma unroll
    for (int j = 0; j < 8; ++j) p[j] = (short)f2bf(T[k8 + j][n]);
    *(s8v*)&Wt[((size_t)nt * 64 + n) * 512 + k0 + k8] = p;
  }
}

// ---------------------------------------------------------------------------
// GEMM1: 256x256 tile, 8 waves (2M x 4N, per-wave 128x64), BK=64, double-
// buffered LDS (128 KB), COUNTED-vmcnt pipeline (T3+T4):
// per tile: issue n(b0,b1) | vmcnt(4)->c0..c5 (B-all,a0,a2) | bar |
//           read B+A_qm0 | 32 MFMA | issue n(b2,b3) | vmcnt(4)->c6,c7 (a1,a3)
//           | bar | read A_qm1 | issue n(a0,a2,a1,a3) | 32 MFMA |
//           lgkmcnt(0)+bar (WAR fence before buffer overwrite).
// Waits only target loads issued a FULL TILE earlier (~640+ cyc of MFMA) ->
// latency hidden; never drains vmcnt to 0 mid-loop (m218: drain-0 == no
// pipeline). Load order [b0,b1,b2,b3,a0,a2,a1,a3] matches consumption.
// Epilogue: q (nb<2) -> normalized qhat; k/v (nb>=2) -> transposed kvT.
// ---------------------------------------------------------------------------
__global__ __launch_bounds__(512, 2)
void gemm_qkv_kernel(const unsigned short* __restrict__ Xbf,
                     const unsigned short* __restrict__ Wt,
                     const float* __restrict__ bq, const float* __restrict__ bk,
                     const float* __restrict__ bv,
                     const float* __restrict__ gamma,
                     unsigned short* __restrict__ qhat,
                     unsigned short* __restrict__ kvT)
{
  __shared__ short As[2][16384];   // 2 x 32 KB (256 rows x 64 K bf16)
  __shared__ short Bs[2][16384];
  const int t = threadIdx.x;
  const int o = blockIdx.x;                    // 1536 blocks
  const int swz = (o & 7) * 192 + (o >> 3);    // bijective XCD swizzle
  const int nb = swz % 6, rb = swz / 6;        // nb fast within XCD chunk
  const int wave = t >> 6, lane = t & 63;
  const int wm = wave & 1, wn = wave >> 1;
  const int quad = lane >> 4, l16 = lane & 15;
  const int row0 = rb * 256, ncol0 = nb * 256;

  const unsigned short* ap[4];
  const unsigned short* bp[4];
  int ldst[4];
  #pragma unroll
  for (int i = 0; i < 4; ++i) {
    int s = i * 512 + t;
    int m = s >> 3, kb = (s & 7) ^ (m & 7);
    ap[i] = Xbf + (size_t)(row0 + m) * 512 + kb * 8;
    bp[i] = Wt + (size_t)(ncol0 + m) * 512 + kb * 8;
    ldst[i] = s * 8;
  }

  f4v acc[8][4];
  #pragma unroll
  for (int i = 0; i < 8; ++i)
    #pragma unroll
    for (int j = 0; j < 4; ++j) acc[i][j] = (f4v){0.f, 0.f, 0.f, 0.f};

  // prologue: stage tile 0 into buf0, order [b0,b1,b2,b3,a0,a2,a1,a3]
  gld16(bp[0], &Bs[0][ldst[0]]);
  gld16(bp[1], &Bs[0][ldst[1]]);
  gld16(bp[2], &Bs[0][ldst[2]]);
  gld16(bp[3], &Bs[0][ldst[3]]);
  gld16(ap[0], &As[0][ldst[0]]);
  gld16(ap[2], &As[0][ldst[2]]);
  gld16(ap[1], &As[0][ldst[1]]);
  gld16(ap[3], &As[0][ldst[3]]);

  for (int kt = 0; kt < 8; ++kt) {
    const bool pf = kt < 7;
    const int cur = kt & 1;
    const short* Ac = As[cur];
    const short* Bc = Bs[cur];
    short* An = (short*)As[cur ^ 1];
    short* Bn = (short*)Bs[cur ^ 1];
    const int koff = (kt + 1) * 64;
    s8v afr[4][2], bfr[4][2];

    // -- issue next-tile b0,b1 (buffer cur^1 free: prev tile's end barrier) --
    if (pf) {
      gld16(bp[0] + koff, &Bn[ldst[0]]);
      gld16(bp[1] + koff, &Bn[ldst[1]]);
    }
    // wait for c0..c5 (B all + a0 + a2); newest 4 = {c6,c7,n0,n1} stay in flight
    if (pf) { WAITVM4(); } else { WAITVM2(); }
    SBAR();

    #pragma unroll
    for (int nj = 0; nj < 4; ++nj)
      #pragma unroll
      for (int ks = 0; ks < 2; ++ks) {
        int r = wn * 64 + nj * 16 + l16;
        bfr[nj][ks] = *(const s8v*)&Bc[(r * 8 + ((ks * 4 + quad) ^ (r & 7))) * 8];
      }
    #pragma unroll
    for (int mi = 0; mi < 4; ++mi)
      #pragma unroll
      for (int ks = 0; ks < 2; ++ks) {
        int r = wm * 128 + mi * 16 + l16;
        afr[mi][ks] = *(const s8v*)&Ac[(r * 8 + ((ks * 4 + quad) ^ (r & 7))) * 8];
      }
    __builtin_amdgcn_s_setprio(1);
    #pragma unroll
    for (int mi = 0; mi < 4; ++mi)
      #pragma unroll
      for (int nj = 0; nj < 4; ++nj)
        #pragma unroll
        for (int ks = 0; ks < 2; ++ks)
          acc[mi][nj] = __builtin_amdgcn_mfma_f32_16x16x32_bf16(afr[mi][ks], bfr[nj][ks], acc[mi][nj], 0, 0, 0);
    __builtin_amdgcn_s_setprio(0);

    // -- issue next-tile b2,b3 --
    if (pf) {
      gld16(bp[2] + koff, &Bn[ldst[2]]);
      gld16(bp[3] + koff, &Bn[ldst[3]]);
    }
    // wait for c6,c7 (a1,a3); newest 4 = {n0..n3} stay in flight
    if (pf) { WAITVM4(); } else { WAITVM0(); }
    SBAR();

    #pragma unroll
    for (int mi = 0; mi < 4; ++mi)
      #pragma unroll
      for (int ks = 0; ks < 2; ++ks) {
        int r = wm * 128 + 64 + mi * 16 + l16;
        afr[mi][ks] = *(const s8v*)&Ac[(r * 8 + ((ks * 4 + quad) ^ (r & 7))) * 8];
      }
    // -- issue next-tile a0,a2,a1,a3 --
    if (pf) {
      gld16(ap[0] + koff, &An[ldst[0]]);
      gld16(ap[2] + koff, &An[ldst[2]]);
      gld16(ap[1] + koff, &An[ldst[1]]);
      gld16(ap[3] + koff, &An[ldst[3]]);
    }
    __builtin_amdgcn_s_setprio(1);
    #pragma unroll
    for (int mi = 0; mi < 4; ++mi)
      #pragma unroll
      for (int nj = 0; nj < 4; ++nj)
        #pragma unroll
        for (int ks = 0; ks < 2; ++ks)
          acc[4 + mi][nj] = __builtin_amdgcn_mfma_f32_16x16x32_bf16(afr[mi][ks], bfr[nj][ks], acc[4 + mi][nj], 0, 0, 0);
    __builtin_amdgcn_s_setprio(0);
    // WAR fence: my ds_reads of buf cur done before any wave overwrites it
    WAITLGKM();
    SBAR();
  }

  if (nb < 2) {
    // q path: bias + per-head normalize * gamma -> qhat (pitch 512)
    #pragma unroll
    for (int nj = 0; nj < 4; ++nj) {
      int colg = ncol0 + wn * 64 + nj * 16 + l16;
      float bias = bq[colg];
      #pragma unroll
      for (int mi = 0; mi < 8; ++mi) {
        acc[mi][nj][0] += bias; acc[mi][nj][1] += bias;
        acc[mi][nj][2] += bias; acc[mi][nj][3] += bias;
      }
    }
    float g = gamma[nb * 4 + wn];
    #pragma unroll
    for (int mi = 0; mi < 8; ++mi)
      #pragma unroll
      for (int rr = 0; rr < 4; ++rr) {
        float ss = acc[mi][0][rr] * acc[mi][0][rr] + acc[mi][1][rr] * acc[mi][1][rr]
                 + acc[mi][2][rr] * acc[mi][2][rr] + acc[mi][3][rr] * acc[mi][3][rr];
        ss += __shfl_xor(ss, 1);
        ss += __shfl_xor(ss, 2);
        ss += __shfl_xor(ss, 4);
        ss += __shfl_xor(ss, 8);
        float scale = g * rsqrtf(ss);
        acc[mi][0][rr] *= scale; acc[mi][1][rr] *= scale;
        acc[mi][2][rr] *= scale; acc[mi][3][rr] *= scale;
      }
    const int colbase = ncol0 + wn * 64;
    #pragma unroll
    for (int mi = 0; mi < 8; ++mi)
      #pragma unroll
      for (int nj = 0; nj < 4; ++nj)
        #pragma unroll
        for (int rr = 0; rr < 4; ++rr) {
          int row = row0 + wm * 128 + mi * 16 + quad * 4 + rr;
          int col = colbase + nj * 16 + l16;
          qhat[(size_t)row * 512 + col] = f2bf(acc[mi][nj][rr]);
        }
  } else {
    // k/v path: bias + transposed store to kvT[sect][bh][dk][n]
    const int sect = (nb - 2) >> 1;                  // 0=k (nb 2,3), 1=v (nb 4,5)
    const float* bb = sect ? bv : bk;
    const int bidx = row0 >> 13;
    const int nrow = (row0 & 8191) + wm * 128 + quad * 4;
    #pragma unroll
    for (int nj = 0; nj < 4; ++nj) {
      int cis = ((nb - 2) & 1) * 256 + wn * 64 + nj * 16 + l16;  // [0,512)
      float bias = bb[cis];
      int h = cis >> 6, dk = cis & 63;
      unsigned short* rowp = kvT + (size_t)((sect * 64 + bidx * 8 + h) * 64 + dk) * 8192;
      #pragma unroll
      for (int mi = 0; mi < 8; ++mi) {
        unsigned int lo = (unsigned int)f2bf(acc[mi][nj][0] + bias)
                        | ((unsigned int)f2bf(acc[mi][nj][1] + bias) << 16);
        unsigned int hi = (unsigned int)f2bf(acc[mi][nj][2] + bias)
                        | ((unsigned int)f2bf(acc[mi][nj][3] + bias) << 16);
        uint2 pk; pk.x = lo; pk.y = hi;
        *(uint2*)&rowp[nrow + mi * 16] = pk;
      }
    }
  }
}

// ---------------------------------------------------------------------------
// kv partials via MFMA straight from global (kvT row-major in n -> coalesced).
// ---------------------------------------------------------------------------
__global__ __launch_bounds__(256)
void kv_accum_kernel(const unsigned short* __restrict__ kvT, float* __restrict__ kvpart)
{
  const int t = threadIdx.x;
  const int bh = blockIdx.x, chunk = blockIdx.y;   // (64, 16)
  const int wave = t >> 6, lane = t & 63;
  const int quad = lane >> 4, l16 = lane & 15;
  const unsigned short* kb_ = kvT + (size_t)bh * 64 * 8192;
  const unsigned short* vb_ = kvT + (size_t)(64 + bh) * 64 * 8192;
  const int n0 = chunk * 512 + wave * 128 + quad * 8;

  f4v acc[4][4];
  #pragma unroll
  for (int i = 0; i < 4; ++i)
    #pragma unroll
    for (int j = 0; j < 4; ++j) acc[i][j] = (f4v){0.f, 0.f, 0.f, 0.f};

  s8v a0[4], b0[4], a1[4], b1[4];
  #pragma unroll
  for (int mi = 0; mi < 4; ++mi) {
    a0[mi] = *(const s8v*)&kb_[(size_t)(mi * 16 + l16) * 8192 + n0];
    b0[mi] = *(const s8v*)&vb_[(size_t)(mi * 16 + l16) * 8192 + n0];
  }

#define KV_STEP(AC, BC, AN, BN, S)                                             \
  {                                                                            \
    if ((S) < 3) {                                                             \
      int nn = n0 + ((S) + 1) * 32;                                            \
      _Pragma("unroll")                                                        \
      for (int mi = 0; mi < 4; ++mi) {                                         \
        AN[mi] = *(const s8v*)&kb_[(size_t)(mi * 16 + l16) * 8192 + nn];       \
        BN[mi] = *(const s8v*)&vb_[(size_t)(mi * 16 + l16) * 8192 + nn];       \
      }                                                                        \
    }                                                                          \
    _Pragma("unroll")                                                          \
    for (int mi = 0; mi < 4; ++mi)                                             \
      _Pragma("unroll")                                                        \
      for (int nj = 0; nj < 4; ++nj)                                           \
        acc[mi][nj] = __builtin_amdgcn_mfma_f32_16x16x32_bf16(AC[mi], BC[nj],  \
                                                              acc[mi][nj], 0, 0, 0); \
  }

  KV_STEP(a0, b0, a1, b1, 0)
  KV_STEP(a1, b1, a0, b0, 1)
  KV_STEP(a0, b0, a1, b1, 2)
  KV_STEP(a1, b1, a0, b0, 3)
#undef KV_STEP

  float* dst = kvpart + ((size_t)(chunk * 4 + wave) * 64 + bh) * 4096;
  #pragma unroll
  for (int mi = 0; mi < 4; ++mi)
    #pragma unroll
    for (int nj = 0; nj < 4; ++nj)
      #pragma unroll
      for (int rr = 0; rr < 4; ++rr)
        dst[(mi * 16 + quad * 4 + rr) * 64 + nj * 16 + l16] = acc[mi][nj][rr];
}

// ---------------------------------------------------------------------------
// reduce 64 slice partials -> kvbuf[bh][4096]. grid (64 bh, 8 seg).
// ---------------------------------------------------------------------------
__global__ __launch_bounds__(256)
void kv_reduce_kernel(const float* __restrict__ kvpart, float* __restrict__ kvbuf)
{
  const int bh = blockIdx.x, seg = blockIdx.y, t = threadIdx.x;
  #pragma unroll
  for (int e = 0; e < 2; ++e) {
    int i = seg * 512 + e * 256 + t;
    float s = 0.f;
    for (int c = 0; c < 64; ++c) s += kvpart[((size_t)c * 64 + bh) * 4096 + i];
    kvbuf[(size_t)bh * 4096 + i] = s;
  }
}

// ---------------------------------------------------------------------------
// W2t[b][d][(h,k)] = sum_v (kv[b,h][k][v]*gamma[h]/||kv row||) * Wo[h*64+v][d]
// ---------------------------------------------------------------------------
__global__ __launch_bounds__(256)
void build_w2t_kernel(const float* __restrict__ kvbuf, const float* __restrict__ Wo,
                      const float* __restrict__ gamma, unsigned short* __restrict__ W2t)
{
  __shared__ float WoS[512][16];
  const int b = blockIdx.x, dt = blockIdx.y;
  const int d0 = dt * 16;
  const int t = threadIdx.x;
  for (int i = 0; i < 32; ++i) {
    int flat = i * 256 + t;
    int rr_ = flat >> 4, c = flat & 15;
    WoS[rr_][c] = Wo[(size_t)rr_ * 512 + d0 + c];
  }
  __syncthreads();
  for (int rr = 0; rr < 2; ++rr) {
    int r = rr * 256 + t;
    int h = r >> 6, k = r & 63;
    const float* krow = kvbuf + ((size_t)b * 8 + h) * 4096 + (size_t)k * 64;
    float ss = 0.f;
    #pragma unroll
    for (int v = 0; v < 64; v += 4) {
      float4 x = *(const float4*)&krow[v];
      ss += x.x * x.x + x.y * x.y + x.z * x.z + x.w * x.w;
    }
    float scale = gamma[h] * rsqrtf(ss);
    f4v accv[4];
    #pragma unroll
    for (int j = 0; j < 4; ++j) accv[j] = (f4v){0.f, 0.f, 0.f, 0.f};
    for (int v = 0; v < 64; ++v) {
      float m = krow[v] * scale;
      const float* w = &WoS[h * 64 + v][0];
      #pragma unroll
      for (int j4 = 0; j4 < 4; ++j4) {
        float4 ww = *(const float4*)&w[j4 * 4];
        accv[j4][0] = fmaf(m, ww.x, accv[j4][0]);
        accv[j4][1] = fmaf(m, ww.y, accv[j4][1]);
        accv[j4][2] = fmaf(m, ww.z, accv[j4][2]);
        accv[j4][3] = fmaf(m, ww.w, accv[j4][3]);
      }
    }
    #pragma unroll
    for (int j = 0; j < 16; ++j)
      W2t[((size_t)b * 512 + d0 + j) * 512 + r] = f2bf(accv[j >> 2][j & 3]);
  }
}

// ---------------------------------------------------------------------------
// GEMM3: Y[b] = qhat[b] @ W2t[b]^T + bo. Same counted-vmcnt schedule as GEMM1.
// ---------------------------------------------------------------------------
__global__ __launch_bounds__(512, 2)
void gemm_out_kernel(const unsigned short* __restrict__ qhat,
                     const unsigned short* __restrict__ W2t,
                     const float* __restrict__ bo,
                     float* __restrict__ out)
{
  __shared__ short As[2][16384];
  __shared__ short Bs[2][16384];
  const int t = threadIdx.x;
  const int o = blockIdx.x;                  // 512 blocks
  const int swz = (o & 7) * 64 + (o >> 3);   // bijective XCD swizzle
  const int nb = swz & 1, rb = swz >> 1;     // nb fast; 32 rb per XCD = 1 batch
  const int wave = t >> 6, lane = t & 63;
  const int wm = wave & 1, wn = wave >> 1;
  const int quad = lane >> 4, l16 = lane & 15;
  const int row0 = rb * 256, ncol0 = nb * 256;
  const unsigned short* Wb = W2t + (size_t)(rb >> 5) * 262144;

  const unsigned short* ap[4];
  const unsigned short* bp[4];
  int ldst[4];
  #pragma unroll
  for (int i = 0; i < 4; ++i) {
    int s = i * 512 + t;
    int m = s >> 3, kb = (s & 7) ^ (m & 7);
    ap[i] = qhat + (size_t)(row0 + m) * 512 + kb * 8;
    bp[i] = Wb + (size_t)(ncol0 + m) * 512 + kb * 8;
    ldst[i] = s * 8;
  }

  f4v acc[8][4];
  #pragma unroll
  for (int i = 0; i < 8; ++i)
    #pragma unroll
    for (int j = 0; j < 4; ++j) acc[i][j] = (f4v){0.f, 0.f, 0.f, 0.f};

  gld16(bp[0], &Bs[0][ldst[0]]);
  gld16(bp[1], &Bs[0][ldst[1]]);
  gld16(bp[2], &Bs[0][ldst[2]]);
  gld16(bp[3], &Bs[0][ldst[3]]);
  gld16(ap[0], &As[0][ldst[0]]);
  gld16(ap[2], &As[0][ldst[2]]);
  gld16(ap[1], &As[0][ldst[1]]);
  gld16(ap[3], &As[0][ldst[3]]);

  for (int kt = 0; kt < 8; ++kt) {
    const bool pf = kt < 7;
    const int cur = kt & 1;
    const short* Ac = As[cur];
    const short* Bc = Bs[cur];
    short* An = (short*)As[cur ^ 1];
    short* Bn = (short*)Bs[cur ^ 1];
    const int koff = (kt + 1) * 64;
    s8v afr[4][2], bfr[4][2];

    if (pf) {
      gld16(bp[0] + koff, &Bn[ldst[0]]);
      gld16(bp[1] + koff, &Bn[ldst[1]]);
    }
    if (pf) { WAITVM4(); } else { WAITVM2(); }
    SBAR();

    #pragma unroll
    for (int nj = 0; nj < 4; ++nj)
      #pragma unroll
      for (int ks = 0; ks < 2; ++ks) {
        int r = wn * 64 + nj * 16 + l16;
        bfr[nj][ks] = *(const s8v*)&Bc[(r * 8 + ((ks * 4 + quad) ^ (r & 7))) * 8];
      }
    #pragma unroll
    for (int mi = 0; mi < 4; ++mi)
      #pragma unroll
      for (int ks = 0; ks < 2; ++ks) {
        int r = wm * 128 + mi * 16 + l16;
        afr[mi][ks] = *(const s8v*)&Ac[(r * 8 + ((ks * 4 + quad) ^ (r & 7))) * 8];
      }
    __builtin_amdgcn_s_setprio(1);
    #pragma unroll
    for (int mi = 0; mi < 4; ++mi)
      #pragma unroll
      for (int nj = 0; nj < 4; ++nj)
        #pragma unroll
        for (int ks = 0; ks < 2; ++ks)
          acc[mi][nj] = __builtin_amdgcn_mfma_f32_16x16x32_bf16(afr[mi][ks], bfr[nj][ks], acc[mi][nj], 0, 0, 0);
    __builtin_amdgcn_s_setprio(0);

    if (pf) {
      gld16(bp[2] + koff, &Bn[ldst[2]]);
      gld16(bp[3] + koff, &Bn[ldst[3]]);
    }
    if (pf) { WAITVM4(); } else { WAITVM0(); }
    SBAR();

    #pragma unroll
    for (int mi = 0; mi < 4; ++mi)
      #pragma unroll
      for (int ks = 0; ks < 2; ++ks) {
        int r = wm * 128 + 64 + mi * 16 + l16;
        afr[mi][ks] = *(const s8v*)&Ac[(r * 8 + ((ks * 4 + quad) ^ (r & 7))) * 8];
      }
    if (pf) {
      gld16(ap[0] + koff, &An[ldst[0]]);
      gld16(ap[2] + koff, &An[ldst[2]]);
      gld16(ap[1] + koff, &An[ldst[1]]);
      gld16(ap[3] + koff, &An[ldst[3]]);
    }
    __builtin_amdgcn_s_setprio(1);
    #pragma unroll
    for (int mi = 0; mi < 4; ++mi)
      #pragma unroll
      for (int nj = 0; nj < 4; ++nj)
        #pragma unroll
        for (int ks = 0; ks < 2; ++ks)
          acc[4 + mi][nj] = __builtin_amdgcn_mfma_f32_16x16x32_bf16(afr[mi][ks], bfr[nj][ks], acc[4 + mi][nj], 0, 0, 0);
    __builtin_amdgcn_s_setprio(0);
    WAITLGKM();
    SBAR();
  }

  const int colbase = ncol0 + wn * 64;
  #pragma unroll
  for (int nj = 0; nj < 4; ++nj) {
    float bias = bo[colbase + nj * 16 + l16];
    #pragma unroll
    for (int mi = 0; mi < 8; ++mi)
      #pragma unroll
      for (int rr = 0; rr < 4; ++rr) {
        int row = row0 + wm * 128 + mi * 16 + quad * 4 + rr;
        int col = colbase + nj * 16 + l16;
        out[(size_t)row * 512 + col] = acc[mi][nj][rr] + bias;
      }
  }
}

// ---------------------------------------------------------------------------
extern "C" void kernel_launch(void* const* d_in, const int* in_sizes, int n_in,
                              void* d_out, int out_size, void* d_ws, size_t ws_size,
                              hipStream_t stream)
{
  (void)in_sizes; (void)n_in; (void)out_size; (void)ws_size;
  const float* X     = (const float*)d_in[0];
  const float* Wq    = (const float*)d_in[1];
  const float* bq    = (const float*)d_in[2];
  const float* Wk    = (const float*)d_in[3];
  const float* bk    = (const float*)d_in[4];
  const float* Wv    = (const float*)d_in[5];
  const float* bv    = (const float*)d_in[6];
  const float* Wo    = (const float*)d_in[7];
  const float* bo    = (const float*)d_in[8];
  const float* gamma = (const float*)d_in[9];

  char* ws = (char*)d_ws;
  unsigned short* qhat = (unsigned short*)ws;                        // 67108864 B
  unsigned short* kvT  = (unsigned short*)(ws + 67108864);           // 134217728 B
  unsigned short* Xbf  = (unsigned short*)(ws + 201326592);          // 67108864 B
  float* kvpart = (float*)(ws + 201326592);                          // aliases Xbf (dead after gemm1): 64 MiB
  unsigned short* Wt  = (unsigned short*)(ws + 201326592 + 67108864);          // 1572864 B
  float* kvbuf        = (float*)(ws + 201326592 + 67108864 + 1572864);         // 1048576 B
  unsigned short* W2t = (unsigned short*)(ws + 201326592 + 67108864 + 1572864 + 1048576); // 4194304 B

  dim3 blk(256);
  convert_x_kernel<<<16384, blk, 0, stream>>>(X, Xbf);
  transpose_w_kernel<<<dim3(8, 24), blk, 0, stream>>>(Wq, Wk, Wv, Wt);
  gemm_qkv_kernel<<<1536, dim3(512), 0, stream>>>(Xbf, Wt, bq, bk, bv, gamma, qhat, kvT);
  kv_accum_kernel<<<dim3(64, 16), blk, 0, stream>>>(kvT, kvpart);
  kv_reduce_kernel<<<dim3(64, 8), blk, 0, stream>>>(kvpart, kvbuf);
  build_w2t_kernel<<<dim3(8, 32), blk, 0, stream>>>(kvbuf, Wo, gamma, W2t);
  gemm_out_kernel<<<512, dim3(512), 0, stream>>>(qhat, W2t, bo, (float*)d_out);
}

// Round 9
// 500.926 us; speedup vs baseline: 1.0311x; 1.0311x over previous
//
#include <hip/hip_runtime.h>

typedef __attribute__((ext_vector_type(8))) short s8v;
typedef __attribute__((ext_vector_type(4))) float f4v;

__device__ __forceinline__ unsigned short f2bf(float f) {
  unsigned int u = __float_as_uint(f);
  u += 0x7FFFu + ((u >> 16) & 1u);   // RNE
  return (unsigned short)(u >> 16);
}
__device__ __forceinline__ float bf2f(unsigned short s) {
  return __uint_as_float(((unsigned int)s) << 16);
}

// async global->LDS 16B: lane i deposits at wave-uniform base + i*16
__device__ __forceinline__ void gld16(const void* g, void* l) {
  __builtin_amdgcn_global_load_lds(
      (const __attribute__((address_space(1))) unsigned int*)g,
      (__attribute__((address_space(3))) unsigned int*)l, 16, 0, 0);
}

// fused wait+barrier (gemm_out template)
#define TILE_SYNC() asm volatile("s_waitcnt vmcnt(0) lgkmcnt(0)\n\ts_barrier" ::: "memory")

// ---------------------------------------------------------------------------
// Pass 0a: X fp32 [65536,512] -> Xbf bf16.
// ---------------------------------------------------------------------------
__global__ __launch_bounds__(256)
void convert_x_kernel(const float* __restrict__ X, unsigned short* __restrict__ Xbf)
{
  size_t base = ((size_t)blockIdx.x * 256 + threadIdx.x) * 8;
  float4 a = *(const float4*)&X[base];
  float4 b = *(const float4*)&X[base + 4];
  s8v p = (s8v){ (short)f2bf(a.x), (short)f2bf(a.y), (short)f2bf(a.z), (short)f2bf(a.w),
                 (short)f2bf(b.x), (short)f2bf(b.y), (short)f2bf(b.z), (short)f2bf(b.w) };
  *(s8v*)&Xbf[base] = p;
}

// ---------------------------------------------------------------------------
// Pass 0b: Wt[n][k] bf16, n = 0..511 Wq | 512..1023 Wk | 1024..1535 Wv.
// ---------------------------------------------------------------------------
__global__ __launch_bounds__(256)
void transpose_w_kernel(const float* __restrict__ Wq, const float* __restrict__ Wk,
                        const float* __restrict__ Wv, unsigned short* __restrict__ Wt)
{
  __shared__ float T[64][68];
  const int kt = blockIdx.x, nt = blockIdx.y;
  const float* W = (nt < 8) ? Wq : (nt < 16 ? Wk : Wv);
  const int n0 = (nt & 7) * 64, k0 = kt * 64;
  const int t = threadIdx.x;
  #pragma unroll
  for (int it = 0; it < 4; ++it) {
    int idx = it * 256 + t;
    int k = idx >> 4, n4 = (idx & 15) << 2;
    *(float4*)&T[k][n4] = *(const float4*)&W[(size_t)(k0 + k) * 512 + n0 + n4];
  }
  __syncthreads();
  #pragma unroll
  for (int it = 0; it < 2; ++it) {
    int idx = it * 256 + t;
    int n = idx >> 3, k8 = (idx & 7) << 3;
    s8v p;
    #pragma unroll
    for (int j = 0; j < 8; ++j) p[j] = (short)f2bf(T[k8 + j][n]);
    *(s8v*)&Wt[((size_t)nt * 64 + n) * 512 + k0 + k8] = p;
  }
}

// ---------------------------------------------------------------------------
// GEMM1 (round-5 measured-best structure: 128x128 tile, 256 thr, single-buffer
// stage->sync->compute, 2.4 blocks/CU do the latency hiding -- rounds 4/7
// falsified both big-tile pipelined variants on this shape).
// Changes vs round 5 (both epilogue/indexing only):
//  1. XCD-bijective 1D swizzle (proven round 3: FETCH 266->45 MB).
//  2. k/v epilogue: wave-local 64x64 LDS transpose (XOR-swizzled) so kvT
//     stores are 128B-contiguous dk-rows instead of 16KB-strided 32B scatter.
// ---------------------------------------------------------------------------
__global__ __launch_bounds__(256, 2)
void gemm_qkv_kernel(const unsigned short* __restrict__ Xbf,
                     const unsigned short* __restrict__ Wt,
                     const float* __restrict__ bq, const float* __restrict__ bk,
                     const float* __restrict__ bv,
                     const float* __restrict__ gamma,
                     unsigned short* __restrict__ qhat,
                     unsigned short* __restrict__ kvT)
{
  __shared__ short As[8192];   // 1024 granules x 16B = 16 KB
  __shared__ short Bs[8192];
  const int t = threadIdx.x;
  const int o = blockIdx.x;                    // 6144 blocks
  const int swz = (o & 7) * 768 + (o >> 3);    // bijective XCD swizzle
  const int nb = swz % 12, rb = swz / 12;      // nb fast: A panel reused 12x in L2
  const int wave = t >> 6, lane = t & 63;
  const int wm = wave & 1, wn = wave >> 1;
  const int quad = lane >> 4, l16 = lane & 15;
  const int row0 = rb * 128;
  const int ncol0 = nb * 128;

  const unsigned short* ap[4];
  const unsigned short* bp[4];
  #pragma unroll
  for (int i = 0; i < 4; ++i) {
    int s = i * 256 + t;
    int m = s >> 3;
    int kb = (s & 7) ^ (m & 7);
    ap[i] = Xbf + (size_t)(row0 + m) * 512 + kb * 8;
    bp[i] = Wt + (size_t)(ncol0 + m) * 512 + kb * 8;
  }

  f4v acc[4][4];
  #pragma unroll
  for (int i = 0; i < 4; ++i)
    #pragma unroll
    for (int j = 0; j < 4; ++j) acc[i][j] = (f4v){0.f, 0.f, 0.f, 0.f};

  for (int kt = 0; kt < 512; kt += 64) {
    __syncthreads();
    #pragma unroll
    for (int i = 0; i < 4; ++i) {
      int s8 = (i * 256 + t) * 8;
      gld16(ap[i] + kt, &As[s8]);
      gld16(bp[i] + kt, &Bs[s8]);
    }
    __syncthreads();
    #pragma unroll
    for (int ks = 0; ks < 2; ++ks) {
      s8v a[4], b[4];
      #pragma unroll
      for (int mi = 0; mi < 4; ++mi) {
        int r = wm * 64 + mi * 16 + l16;
        int slot = r * 8 + ((ks * 4 + quad) ^ (r & 7));
        a[mi] = *(const s8v*)&As[slot * 8];
      }
      #pragma unroll
      for (int nj = 0; nj < 4; ++nj) {
        int r = wn * 64 + nj * 16 + l16;
        int slot = r * 8 + ((ks * 4 + quad) ^ (r & 7));
        b[nj] = *(const s8v*)&Bs[slot * 8];
      }
      #pragma unroll
      for (int mi = 0; mi < 4; ++mi)
        #pragma unroll
        for (int nj = 0; nj < 4; ++nj)
          acc[mi][nj] = __builtin_amdgcn_mfma_f32_16x16x32_bf16(a[mi], b[nj], acc[mi][nj], 0, 0, 0);
    }
  }

  if (nb < 4) {
    // q path: bias + per-head normalize * gamma, store qhat (pitch 512)
    #pragma unroll
    for (int nj = 0; nj < 4; ++nj) {
      int colg = ncol0 + wn * 64 + nj * 16 + l16;
      float bias = bq[colg];
      #pragma unroll
      for (int mi = 0; mi < 4; ++mi) {
        acc[mi][nj][0] += bias; acc[mi][nj][1] += bias;
        acc[mi][nj][2] += bias; acc[mi][nj][3] += bias;
      }
    }
    float g = gamma[nb * 2 + wn];
    #pragma unroll
    for (int mi = 0; mi < 4; ++mi)
      #pragma unroll
      for (int rr = 0; rr < 4; ++rr) {
        float ss = acc[mi][0][rr] * acc[mi][0][rr] + acc[mi][1][rr] * acc[mi][1][rr]
                 + acc[mi][2][rr] * acc[mi][2][rr] + acc[mi][3][rr] * acc[mi][3][rr];
        ss += __shfl_xor(ss, 1);
        ss += __shfl_xor(ss, 2);
        ss += __shfl_xor(ss, 4);
        ss += __shfl_xor(ss, 8);
        float scale = g * rsqrtf(ss);
        acc[mi][0][rr] *= scale; acc[mi][1][rr] *= scale;
        acc[mi][2][rr] *= scale; acc[mi][3][rr] *= scale;
      }
    const int colbase = ncol0 + wn * 64;
    #pragma unroll
    for (int mi = 0; mi < 4; ++mi)
      #pragma unroll
      for (int nj = 0; nj < 4; ++nj)
        #pragma unroll
        for (int rr = 0; rr < 4; ++rr) {
          int row = row0 + wm * 64 + mi * 16 + quad * 4 + rr;
          int col = colbase + nj * 16 + l16;
          qhat[(size_t)row * 512 + col] = f2bf(acc[mi][nj][rr]);
        }
  } else {
    // k/v path: bias, then wave-local 64x64 LDS transpose -> coalesced kvT.
    // Wave owns local n (ln 0..63, = mi*16+quad*4+rr) x dk (ld 0..63,
    // = nj*16+l16) of head h. LDS slot (XOR-swizzled within dk-row):
    // base[ld*64 + (ln4 ^ ((ld&15)<<2))] holds 4 bf16 of n-group ln4.
    const int sect = (nb - 4) >> 2;                  // 0=k, 1=v
    const float* bb = sect ? bv : bk;
    const int bidx = row0 >> 13;
    const int cis0 = ((nb - 4) & 3) * 128 + wn * 64; // multiple of 64
    const int h = cis0 >> 6;
    short* base = (wave < 2) ? &As[wave * 4096] : &Bs[(wave - 2) * 4096];
    __syncthreads();   // all waves done reading As/Bs in the K-loop
    #pragma unroll
    for (int nj = 0; nj < 4; ++nj) {
      int ld = nj * 16 + l16;
      float bias = bb[cis0 + ld];
      int c = (ld & 15) << 2;
      #pragma unroll
      for (int mi = 0; mi < 4; ++mi) {
        int ln4 = mi * 16 + quad * 4;
        unsigned int lo = (unsigned int)f2bf(acc[mi][nj][0] + bias)
                        | ((unsigned int)f2bf(acc[mi][nj][1] + bias) << 16);
        unsigned int hi = (unsigned int)f2bf(acc[mi][nj][2] + bias)
                        | ((unsigned int)f2bf(acc[mi][nj][3] + bias) << 16);
        uint2 pk; pk.x = lo; pk.y = hi;
        *(uint2*)&base[ld * 64 + (ln4 ^ c)] = pk;
      }
    }
    __syncthreads();
    const int nbase = (row0 & 8191) + wm * 64;
    unsigned short* secp = kvT + (size_t)((sect * 64 + bidx * 8 + h) * 64) * 8192;
    #pragma unroll
    for (int pass = 0; pass < 16; ++pass) {
      int rowd = pass * 4 + (lane >> 4);        // dk row 0..63
      int ng = (lane & 15) * 4;                 // n group within wave
      int c2 = (rowd & 15) << 2;
      uint2 v = *(const uint2*)&base[rowd * 64 + (ng ^ c2)];
      *(uint2*)&secp[(size_t)rowd * 8192 + nbase + ng] = v;   // 16 lanes = 128B
    }
  }
}

// ---------------------------------------------------------------------------
// kv partials via MFMA straight from global (kvT row-major in n -> coalesced).
// ---------------------------------------------------------------------------
__global__ __launch_bounds__(256)
void kv_accum_kernel(const unsigned short* __restrict__ kvT, float* __restrict__ kvpart)
{
  const int t = threadIdx.x;
  const int bh = blockIdx.x, chunk = blockIdx.y;   // (64, 16)
  const int wave = t >> 6, lane = t & 63;
  const int quad = lane >> 4, l16 = lane & 15;
  const unsigned short* kb_ = kvT + (size_t)bh * 64 * 8192;
  const unsigned short* vb_ = kvT + (size_t)(64 + bh) * 64 * 8192;
  const int n0 = chunk * 512 + wave * 128 + quad * 8;

  f4v acc[4][4];
  #pragma unroll
  for (int i = 0; i < 4; ++i)
    #pragma unroll
    for (int j = 0; j < 4; ++j) acc[i][j] = (f4v){0.f, 0.f, 0.f, 0.f};

  s8v a0[4], b0[4], a1[4], b1[4];
  #pragma unroll
  for (int mi = 0; mi < 4; ++mi) {
    a0[mi] = *(const s8v*)&kb_[(size_t)(mi * 16 + l16) * 8192 + n0];
    b0[mi] = *(const s8v*)&vb_[(size_t)(mi * 16 + l16) * 8192 + n0];
  }

#define KV_STEP(AC, BC, AN, BN, S)                                             \
  {                                                                            \
    if ((S) < 3) {                                                             \
      int nn = n0 + ((S) + 1) * 32;                                            \
      _Pragma("unroll")                                                        \
      for (int mi = 0; mi < 4; ++mi) {                                         \
        AN[mi] = *(const s8v*)&kb_[(size_t)(mi * 16 + l16) * 8192 + nn];       \
        BN[mi] = *(const s8v*)&vb_[(size_t)(mi * 16 + l16) * 8192 + nn];       \
      }                                                                        \
    }                                                                          \
    _Pragma("unroll")                                                          \
    for (int mi = 0; mi < 4; ++mi)                                             \
      _Pragma("unroll")                                                        \
      for (int nj = 0; nj < 4; ++nj)                                           \
        acc[mi][nj] = __builtin_amdgcn_mfma_f32_16x16x32_bf16(AC[mi], BC[nj],  \
                                                              acc[mi][nj], 0, 0, 0); \
  }

  KV_STEP(a0, b0, a1, b1, 0)
  KV_STEP(a1, b1, a0, b0, 1)
  KV_STEP(a0, b0, a1, b1, 2)
  KV_STEP(a1, b1, a0, b0, 3)
#undef KV_STEP

  float* dst = kvpart + ((size_t)(chunk * 4 + wave) * 64 + bh) * 4096;
  #pragma unroll
  for (int mi = 0; mi < 4; ++mi)
    #pragma unroll
    for (int nj = 0; nj < 4; ++nj)
      #pragma unroll
      for (int rr = 0; rr < 4; ++rr)
        dst[(mi * 16 + quad * 4 + rr) * 64 + nj * 16 + l16] = acc[mi][nj][rr];
}

// ---------------------------------------------------------------------------
// reduce 64 slice partials -> kvbuf[bh][4096]. grid (64 bh, 8 seg).
// ---------------------------------------------------------------------------
__global__ __launch_bounds__(256)
void kv_reduce_kernel(const float* __restrict__ kvpart, float* __restrict__ kvbuf)
{
  const int bh = blockIdx.x, seg = blockIdx.y, t = threadIdx.x;
  #pragma unroll
  for (int e = 0; e < 2; ++e) {
    int i = seg * 512 + e * 256 + t;
    float s = 0.f;
    for (int c = 0; c < 64; ++c) s += kvpart[((size_t)c * 64 + bh) * 4096 + i];
    kvbuf[(size_t)bh * 4096 + i] = s;
  }
}

// ---------------------------------------------------------------------------
// W2t[b][d][(h,k)] = sum_v (kv[b,h][k][v]*gamma[h]/||kv row||) * Wo[h*64+v][d]
// ---------------------------------------------------------------------------
__global__ __launch_bounds__(256)
void build_w2t_kernel(const float* __restrict__ kvbuf, const float* __restrict__ Wo,
                      const float* __restrict__ gamma, unsigned short* __restrict__ W2t)
{
  __shared__ float WoS[512][16];
  const int b = blockIdx.x, dt = blockIdx.y;
  const int d0 = dt * 16;
  const int t = threadIdx.x;
  for (int i = 0; i < 32; ++i) {
    int flat = i * 256 + t;
    int rr_ = flat >> 4, c = flat & 15;
    WoS[rr_][c] = Wo[(size_t)rr_ * 512 + d0 + c];
  }
  __syncthreads();
  for (int rr = 0; rr < 2; ++rr) {
    int r = rr * 256 + t;
    int h = r >> 6, k = r & 63;
    const float* krow = kvbuf + ((size_t)b * 8 + h) * 4096 + (size_t)k * 64;
    float ss = 0.f;
    #pragma unroll
    for (int v = 0; v < 64; v += 4) {
      float4 x = *(const float4*)&krow[v];
      ss += x.x * x.x + x.y * x.y + x.z * x.z + x.w * x.w;
    }
    float scale = gamma[h] * rsqrtf(ss);
    f4v accv[4];
    #pragma unroll
    for (int j = 0; j < 4; ++j) accv[j] = (f4v){0.f, 0.f, 0.f, 0.f};
    for (int v = 0; v < 64; ++v) {
      float m = krow[v] * scale;
      const float* w = &WoS[h * 64 + v][0];
      #pragma unroll
      for (int j4 = 0; j4 < 4; ++j4) {
        float4 ww = *(const float4*)&w[j4 * 4];
        accv[j4][0] = fmaf(m, ww.x, accv[j4][0]);
        accv[j4][1] = fmaf(m, ww.y, accv[j4][1]);
        accv[j4][2] = fmaf(m, ww.z, accv[j4][2]);
        accv[j4][3] = fmaf(m, ww.w, accv[j4][3]);
      }
    }
    #pragma unroll
    for (int j = 0; j < 16; ++j)
      W2t[((size_t)b * 512 + d0 + j) * 512 + r] = f2bf(accv[j >> 2][j & 3]);
  }
}

// ---------------------------------------------------------------------------
// GEMM3: Y[b] = qhat[b] @ W2t[b]^T + bo, fp32 out. Round-5 measured version
// (256x256, 4-phase).
// ---------------------------------------------------------------------------
__global__ __launch_bounds__(512, 2)
void gemm_out_kernel(const unsigned short* __restrict__ qhat,
                     const unsigned short* __restrict__ W2t,
                     const float* __restrict__ bo,
                     float* __restrict__ out)
{
  __shared__ short As[2][16384];
  __shared__ short Bs[2][16384];
  const int t = threadIdx.x;
  const int o = blockIdx.x;                  // 512 blocks
  const int swz = (o & 7) * 64 + (o >> 3);   // bijective XCD swizzle
  const int nb = swz & 1, rb = swz >> 1;     // nb fast; 32 rb per XCD = 1 batch
  const int wave = t >> 6, lane = t & 63;
  const int wm = wave & 1, wn = wave >> 1;
  const int quad = lane >> 4, l16 = lane & 15;
  const int row0 = rb * 256, ncol0 = nb * 256;
  const unsigned short* Wb = W2t + (size_t)(rb >> 5) * 262144;

  const unsigned short* ap[4];
  const unsigned short* bp[4];
  int ldst[4];
  #pragma unroll
  for (int i = 0; i < 4; ++i) {
    int s = i * 512 + t;
    int m = s >> 3, kb = (s & 7) ^ (m & 7);
    ap[i] = qhat + (size_t)(row0 + m) * 512 + kb * 8;
    bp[i] = Wb + (size_t)(ncol0 + m) * 512 + kb * 8;
    ldst[i] = s * 8;
  }

  f4v acc[8][4];
  #pragma unroll
  for (int i = 0; i < 8; ++i)
    #pragma unroll
    for (int j = 0; j < 4; ++j) acc[i][j] = (f4v){0.f, 0.f, 0.f, 0.f};

  #pragma unroll
  for (int i = 0; i < 4; ++i) {
    gld16(ap[i], &As[0][ldst[i]]);
    gld16(bp[i], &Bs[0][ldst[i]]);
  }
  TILE_SYNC();

  for (int kt = 0; kt < 8; ++kt) {
    const int cur = kt & 1;
    const short* Ac = As[cur];
    const short* Bc = Bs[cur];
    short* An = (short*)As[cur ^ 1];
    short* Bn = (short*)Bs[cur ^ 1];
    const int koff = (kt + 1) * 64;
    const bool pf = kt < 7;
    s8v afr[4][2], bfr[4][2];

    // phase 0
    if (pf) {
      gld16(ap[0] + koff, &An[ldst[0]]);
      gld16(ap[1] + koff, &An[ldst[1]]);
      gld16(bp[0] + koff, &Bn[ldst[0]]);
      gld16(bp[1] + koff, &Bn[ldst[1]]);
    }
    #pragma unroll
    for (int nj = 0; nj < 4; ++nj)
      #pragma unroll
      for (int ks = 0; ks < 2; ++ks) {
        int r = wn * 64 + nj * 16 + l16;
        bfr[nj][ks] = *(const s8v*)&Bc[(r * 8 + ((ks * 4 + quad) ^ (r & 7))) * 8];
      }
    #pragma unroll
    for (int mi = 0; mi < 4; ++mi)
      #pragma unroll
      for (int ks = 0; ks < 2; ++ks) {
        int r = wm * 128 + mi * 16 + l16;
        afr[mi][ks] = *(const s8v*)&Ac[(r * 8 + ((ks * 4 + quad) ^ (r & 7))) * 8];
      }
    __builtin_amdgcn_s_setprio(1);
    #pragma unroll
    for (int mi = 0; mi < 4; ++mi)
      #pragma unroll
      for (int nj = 0; nj < 2; ++nj)
        #pragma unroll
        for (int ks = 0; ks < 2; ++ks)
          acc[mi][nj] = __builtin_amdgcn_mfma_f32_16x16x32_bf16(afr[mi][ks], bfr[nj][ks], acc[mi][nj], 0, 0, 0);
    __builtin_amdgcn_s_setprio(0);
    __builtin_amdgcn_s_barrier();

    // phase 1
    if (pf) {
      gld16(ap[2] + koff, &An[ldst[2]]);
      gld16(ap[3] + koff, &An[ldst[3]]);
      gld16(bp[2] + koff, &Bn[ldst[2]]);
      gld16(bp[3] + koff, &Bn[ldst[3]]);
    }
    __builtin_amdgcn_s_setprio(1);
    #pragma unroll
    for (int mi = 0; mi < 4; ++mi)
      #pragma unroll
      for (int nj = 2; nj < 4; ++nj)
        #pragma unroll
        for (int ks = 0; ks < 2; ++ks)
          acc[mi][nj] = __builtin_amdgcn_mfma_f32_16x16x32_bf16(afr[mi][ks], bfr[nj][ks], acc[mi][nj], 0, 0, 0);
    __builtin_amdgcn_s_setprio(0);
    __builtin_amdgcn_s_barrier();

    // phase 2
    #pragma unroll
    for (int mi = 0; mi < 4; ++mi)
      #pragma unroll
      for (int ks = 0; ks < 2; ++ks) {
        int r = wm * 128 + (4 + mi) * 16 + l16;
        afr[mi][ks] = *(const s8v*)&Ac[(r * 8 + ((ks * 4 + quad) ^ (r & 7))) * 8];
      }
    __builtin_amdgcn_s_setprio(1);
    #pragma unroll
    for (int mi = 0; mi < 4; ++mi)
      #pragma unroll
      for (int nj = 0; nj < 2; ++nj)
        #pragma unroll
        for (int ks = 0; ks < 2; ++ks)
          acc[4 + mi][nj] = __builtin_amdgcn_mfma_f32_16x16x32_bf16(afr[mi][ks], bfr[nj][ks], acc[4 + mi][nj], 0, 0, 0);
    __builtin_amdgcn_s_setprio(0);
    __builtin_amdgcn_s_barrier();

    // phase 3
    __builtin_amdgcn_s_setprio(1);
    #pragma unroll
    for (int mi = 0; mi < 4; ++mi)
      #pragma unroll
      for (int nj = 2; nj < 4; ++nj)
        #pragma unroll
        for (int ks = 0; ks < 2; ++ks)
          acc[4 + mi][nj] = __builtin_amdgcn_mfma_f32_16x16x32_bf16(afr[mi][ks], bfr[nj][ks], acc[4 + mi][nj], 0, 0, 0);
    __builtin_amdgcn_s_setprio(0);
    TILE_SYNC();
  }

  const int colbase = ncol0 + wn * 64;
  #pragma unroll
  for (int nj = 0; nj < 4; ++nj) {
    float bias = bo[colbase + nj * 16 + l16];
    #pragma unroll
    for (int mi = 0; mi < 8; ++mi)
      #pragma unroll
      for (int rr = 0; rr < 4; ++rr) {
        int row = row0 + wm * 128 + mi * 16 + quad * 4 + rr;
        int col = colbase + nj * 16 + l16;
        out[(size_t)row * 512 + col] = acc[mi][nj][rr] + bias;
      }
  }
}

// ---------------------------------------------------------------------------
extern "C" void kernel_launch(void* const* d_in, const int* in_sizes, int n_in,
                              void* d_out, int out_size, void* d_ws, size_t ws_size,
                              hipStream_t stream)
{
  (void)in_sizes; (void)n_in; (void)out_size; (void)ws_size;
  const float* X     = (const float*)d_in[0];
  const float* Wq    = (const float*)d_in[1];
  const float* bq    = (const float*)d_in[2];
  const float* Wk    = (const float*)d_in[3];
  const float* bk    = (const float*)d_in[4];
  const float* Wv    = (const float*)d_in[5];
  const float* bv    = (const float*)d_in[6];
  const float* Wo    = (const float*)d_in[7];
  const float* bo    = (const float*)d_in[8];
  const float* gamma = (const float*)d_in[9];

  char* ws = (char*)d_ws;
  unsigned short* qhat = (unsigned short*)ws;                        // 67108864 B
  unsigned short* kvT  = (unsigned short*)(ws + 67108864);           // 134217728 B
  unsigned short* Xbf  = (unsigned short*)(ws + 201326592);          // 67108864 B
  float* kvpart = (float*)(ws + 201326592);                          // aliases Xbf (dead after gemm1): 64 MiB
  unsigned short* Wt  = (unsigned short*)(ws + 201326592 + 67108864);          // 1572864 B
  float* kvbuf        = (float*)(ws + 201326592 + 67108864 + 1572864);         // 1048576 B
  unsigned short* W2t = (unsigned short*)(ws + 201326592 + 67108864 + 1572864 + 1048576); // 4194304 B

  dim3 blk(256);
  convert_x_kernel<<<16384, blk, 0, stream>>>(X, Xbf);
  transpose_w_kernel<<<dim3(8, 24), blk, 0, stream>>>(Wq, Wk, Wv, Wt);
  gemm_qkv_kernel<<<6144, blk, 0, stream>>>(Xbf, Wt, bq, bk, bv, gamma, qhat, kvT);
  kv_accum_kernel<<<dim3(64, 16), blk, 0, stream>>>(kvT, kvpart);
  kv_reduce_kernel<<<dim3(64, 8), blk, 0, stream>>>(kvpart, kvbuf);
  build_w2t_kernel<<<dim3(8, 32), blk, 0, stream>>>(kvbuf, Wo, gamma, W2t);
  gemm_out_kernel<<<512, dim3(512), 0, stream>>>(qhat, W2t, bo, (float*)d_out);
}